// Round 7
// baseline (81.750 us; speedup 1.0000x reference)
//
#include <hip/hip_runtime.h>
#include <hip/hip_bf16.h>

constexpr int NBATCH = 2048;   // B*T
constexpr int N      = 128;    // nodes
constexpr float INVTAU = 20.0f;   // 1/0.05
constexpr float EPSF   = 1e-8f;
constexpr float MUF    = 1.0f / 128.0f;   // mu = nu = 1/N

typedef __attribute__((ext_vector_type(8))) short short8;   // 8 x bf16 MFMA frag
typedef __attribute__((ext_vector_type(4))) float f32x4;    // MFMA accumulator
typedef __attribute__((ext_vector_type(2))) float f32x2;    // packed pair -> v_pk_fma_f32

static __device__ __forceinline__ float fastrcp(float x) {
    return __builtin_amdgcn_rcpf(x);    // v_rcp_f32, ~1e-7 rel err
}
static __device__ __forceinline__ float fastsqrt(float x) {
    return __builtin_amdgcn_sqrtf(x);   // raw v_sqrt_f32
}

// TWO batches per block (latency-bound fix, r6 post-mortem: VALUBusy 37%,
// 63% stall — every dependent chain gets an independent sibling chain).
// 512 threads = 8 waves; per batch g: wave w owns C rows 16w..16w+15 x 128 cols.
// Lane (lx=l&15, lh=l>>4) owns rows 16w+4lh+q (q<4), cols 16tc+lx (tc<8).
// LDS: 64KB staging (bf16, XOR-swizzled), overlaid by sPart after MFMA phase.
// K as f32x2 pairs (packed FMA), C packed bf16. bounds(512,4): cap 128, no spill.
__global__ __launch_bounds__(512, 4)
void sinkhorn_batch(const float* __restrict__ srcg,
                    const float* __restrict__ tgtg,
                    float* __restrict__ lossg)
{
    // staging: [g][{A,B}][128 rows][64 k], swizzled; reused as sPart in phase 3
    __shared__ ushort sStage[4 * N * 64];          // 64 KB
    __shared__ float sX2[2][N], sY2[2][N], sV[2][N];
    __shared__ float sRed[2][8];

    const int t  = threadIdx.x;
    const int l  = t & 63;
    const int w  = t >> 6;       // wave 0..7
    const int lx = l & 15;
    const int lh = l >> 4;       // 0..3
    const int bt0 = blockIdx.x * 2;

    // ---- phase 0: stage both batches bf16 (swizzled) + fp32 row norms ----
    #pragma unroll
    for (int it = 0; it < 8; ++it) {
        const int g = it >> 2;
        const int f = t + 512 * (it & 3);     // 0..2047 float4s
        const float4* sg4 = reinterpret_cast<const float4*>(srcg + (size_t)(bt0 + g) * (N * 64));
        const float4* tg4 = reinterpret_cast<const float4*>(tgtg + (size_t)(bt0 + g) * (N * 64));
        int r  = f >> 4;
        int d4 = f & 15;
        float4 a = sg4[f];
        float4 b = tg4[f];
        float pa = a.x * a.x + a.y * a.y + a.z * a.z + a.w * a.w;
        float pb = b.x * b.x + b.y * b.y + b.z * b.z + b.w * b.w;
        float x = (lx & 8) ? pb : pa;
        float y = (lx & 8) ? pa : pb;
        x += __shfl_xor(y, 8);
        x += __shfl_xor(x, 1);
        x += __shfl_xor(x, 2);
        x += __shfl_xor(x, 4);
        if ((lx & 7) == 0) ((lx & 8) ? sY2[g] : sX2[g])[r] = x;

        int idx = r * 64 + (((d4 >> 1) ^ (r & 7)) << 3) + (d4 & 1) * 4;
        union { __hip_bfloat162 h[2]; ushort4 u; } ca, cb;
        ca.h[0] = __float22bfloat162_rn(make_float2(a.x, a.y));
        ca.h[1] = __float22bfloat162_rn(make_float2(a.z, a.w));
        cb.h[0] = __float22bfloat162_rn(make_float2(b.x, b.y));
        cb.h[1] = __float22bfloat162_rn(make_float2(b.z, b.w));
        *reinterpret_cast<ushort4*>(&sStage[(g * 2 + 0) * (N * 64) + idx]) = ca.u;
        *reinterpret_cast<ushort4*>(&sStage[(g * 2 + 1) * (N * 64) + idx]) = cb.u;
    }
    __syncthreads();

    // ---- phase 1+2 fused: per batch, per col-tile MFMA -> C,K ----
    f32x2 kk2[2][8][2];      // kk2[g][tc][p] = {K[q=2p], K[q=2p+1]}
    unsigned ccp[2][8][2];   // packed bf16 C
    #pragma unroll
    for (int g = 0; g < 2; ++g) {
        const ushort* sAg = &sStage[(g * 2 + 0) * (N * 64)];
        const ushort* sBg = &sStage[(g * 2 + 1) * (N * 64)];
        float x2r[4], y2c[8];
        #pragma unroll
        for (int q = 0; q < 4; ++q) x2r[q] = sX2[g][16 * w + 4 * lh + q];
        #pragma unroll
        for (int tc = 0; tc < 8; ++tc) y2c[tc] = sY2[g][16 * tc + lx];

        int ra = 16 * w + lx;
        short8 af0 = *reinterpret_cast<const short8*>(&sAg[ra * 64 + (((0 + lh) ^ (ra & 7)) << 3)]);
        short8 af1 = *reinterpret_cast<const short8*>(&sAg[ra * 64 + (((4 + lh) ^ (ra & 7)) << 3)]);

        #pragma unroll
        for (int tc = 0; tc < 8; ++tc) {
            int rb = 16 * tc + lx;
            short8 bf0 = *reinterpret_cast<const short8*>(&sBg[rb * 64 + (((0 + lh) ^ (rb & 7)) << 3)]);
            short8 bf1 = *reinterpret_cast<const short8*>(&sBg[rb * 64 + (((4 + lh) ^ (rb & 7)) << 3)]);
            f32x4 acc = (f32x4){0.f, 0.f, 0.f, 0.f};
            acc = __builtin_amdgcn_mfma_f32_16x16x32_bf16(af0, bf0, acc, 0, 0, 0);
            acc = __builtin_amdgcn_mfma_f32_16x16x32_bf16(af1, bf1, acc, 0, 0, 0);
            float cd[4];
            #pragma unroll
            for (int q = 0; q < 4; ++q) {
                float d2 = x2r[q] + y2c[tc] - 2.0f * acc[q];
                cd[q] = fastsqrt(fmaxf(d2, 0.f));
            }
            kk2[g][tc][0] = (f32x2){__expf(-INVTAU * cd[0]), __expf(-INVTAU * cd[1])};
            kk2[g][tc][1] = (f32x2){__expf(-INVTAU * cd[2]), __expf(-INVTAU * cd[3])};
            union { __hip_bfloat162 h; unsigned u; } p0, p1;
            p0.h = __float22bfloat162_rn(make_float2(cd[0], cd[1]));
            p1.h = __float22bfloat162_rn(make_float2(cd[2], cd[3]));
            ccp[g][tc][0] = p0.u;
            ccp[g][tc][1] = p1.u;
        }
    }

    if (t < 2 * N) sV[t >> 7][t & 127] = 1.0f;
    __syncthreads();   // staging reads done -> region becomes sPart

    float* sPartF = reinterpret_cast<float*>(sStage);   // [g][w][tc][lx] = 8 KB

    // ---- phase 3: Sinkhorn; u register-resident; both batches interleaved ----
    f32x2 uu2[2][2];
    for (int iter = 0; iter < 5; ++iter) {
        // u = mu / (K v + eps): reduce over cols (lx in-wave)
        #pragma unroll
        for (int g = 0; g < 2; ++g) {
            float vv[8];
            #pragma unroll
            for (int tc = 0; tc < 8; ++tc) vv[tc] = sV[g][16 * tc + lx];
            f32x2 p0 = (f32x2){0.f, 0.f}, p1 = (f32x2){0.f, 0.f};
            #pragma unroll
            for (int tc = 0; tc < 8; ++tc) {
                f32x2 vb = (f32x2){vv[tc], vv[tc]};
                p0 = kk2[g][tc][0] * vb + p0;      // v_pk_fma_f32
                p1 = kk2[g][tc][1] * vb + p1;
            }
            float s0 = p0.x, s1 = p0.y, s2 = p1.x, s3 = p1.y;
            s0 += __shfl_xor(s0, 1); s1 += __shfl_xor(s1, 1); s2 += __shfl_xor(s2, 1); s3 += __shfl_xor(s3, 1);
            s0 += __shfl_xor(s0, 2); s1 += __shfl_xor(s1, 2); s2 += __shfl_xor(s2, 2); s3 += __shfl_xor(s3, 2);
            s0 += __shfl_xor(s0, 4); s1 += __shfl_xor(s1, 4); s2 += __shfl_xor(s2, 4); s3 += __shfl_xor(s3, 4);
            s0 += __shfl_xor(s0, 8); s1 += __shfl_xor(s1, 8); s2 += __shfl_xor(s2, 8); s3 += __shfl_xor(s3, 8);
            uu2[g][0] = (f32x2){MUF * fastrcp(s0 + EPSF), MUF * fastrcp(s1 + EPSF)};
            uu2[g][1] = (f32x2){MUF * fastrcp(s2 + EPSF), MUF * fastrcp(s3 + EPSF)};
        }

        // v = nu / (K^T u + eps): in-wave over rows, then cross-wave via sPart
        #pragma unroll
        for (int g = 0; g < 2; ++g)
            #pragma unroll
            for (int tc = 0; tc < 8; ++tc) {
                f32x2 t2 = kk2[g][tc][0] * uu2[g][0] + kk2[g][tc][1] * uu2[g][1];
                float qc = t2.x + t2.y;
                qc += __shfl_xor(qc, 16);
                qc += __shfl_xor(qc, 32);
                if (l < 16) sPartF[((g * 8 + w) * 8 + tc) * 16 + lx] = qc;
            }
        __syncthreads();
        if (t < 2 * N) {
            int g = t >> 7, i = t & 127, b = i >> 4, x = i & 15;
            float s = 0.f;
            #pragma unroll
            for (int ww = 0; ww < 8; ++ww)
                s += sPartF[((g * 8 + ww) * 8 + b) * 16 + x];
            sV[g][i] = MUF * fastrcp(s + EPSF);
        }
        __syncthreads();
    }

    // ---- phase 4: loss = sum u K C v (u, K, C register-resident) ----
    float part[2];
    #pragma unroll
    for (int g = 0; g < 2; ++g) {
        float vc[8];
        #pragma unroll
        for (int tc = 0; tc < 8; ++tc) vc[tc] = sV[g][16 * tc + lx];
        float p = 0.f;
        #pragma unroll
        for (int tc = 0; tc < 8; ++tc) {
            union { unsigned u; float f; } e0, e1, e2, e3;
            e0.u = ccp[g][tc][0] << 16;
            e1.u = ccp[g][tc][0] & 0xFFFF0000u;
            e2.u = ccp[g][tc][1] << 16;
            e3.u = ccp[g][tc][1] & 0xFFFF0000u;
            f32x2 c0 = (f32x2){e0.f, e1.f};
            f32x2 c1 = (f32x2){e2.f, e3.f};
            f32x2 r2 = uu2[g][0] * kk2[g][tc][0] * c0 + uu2[g][1] * kk2[g][tc][1] * c1;
            p += (r2.x + r2.y) * vc[tc];
        }
        part[g] = p;
    }

    // deterministic block reduce (both batches)
    #pragma unroll
    for (int g = 0; g < 2; ++g) {
        float p = part[g];
        #pragma unroll
        for (int off = 32; off >= 1; off >>= 1)
            p += __shfl_xor(p, off);
        if (l == 0) sRed[g][w] = p;
    }
    __syncthreads();
    if (t < 2) {
        float s = 0.f;
        #pragma unroll
        for (int i = 0; i < 8; ++i) s += sRed[t][i];
        lossg[bt0 + t] = s;
    }
}

// mean over 2048 per-frame losses -> d_out[0]
__global__ __launch_bounds__(256, 1)
void reduce_mean(const float* __restrict__ lossg, float* __restrict__ out)
{
    __shared__ float sRed[4];
    int t = threadIdx.x;
    float s = 0.f;
    #pragma unroll
    for (int it = 0; it < 8; ++it) s += lossg[t + 256 * it];
    #pragma unroll
    for (int off = 32; off >= 1; off >>= 1) s += __shfl_xor(s, off);
    if ((t & 63) == 0) sRed[t >> 6] = s;
    __syncthreads();
    if (t == 0) out[0] = (sRed[0] + sRed[1] + sRed[2] + sRed[3]) * (1.0f / 2048.0f);
}

extern "C" void kernel_launch(void* const* d_in, const int* in_sizes, int n_in,
                              void* d_out, int out_size, void* d_ws, size_t ws_size,
                              hipStream_t stream)
{
    const float* src = (const float*)d_in[0];
    const float* tgt = (const float*)d_in[1];
    float* ws = (float*)d_ws;                       // 2048 floats of scratch

    sinkhorn_batch<<<NBATCH / 2, 512, 0, stream>>>(src, tgt, ws);
    reduce_mean<<<1, 256, 0, stream>>>(ws, (float*)d_out);
}

// Round 8
// 69.573 us; speedup vs baseline: 1.1750x; 1.1750x over previous
//
#include <hip/hip_runtime.h>
#include <hip/hip_bf16.h>

constexpr int NBATCH = 2048;   // B*T
constexpr int N      = 128;    // nodes
constexpr float INVTAU = 20.0f;   // 1/0.05
constexpr float EPSF   = 1e-8f;
constexpr float MUF    = 1.0f / 128.0f;   // mu = nu = 1/N

typedef __attribute__((ext_vector_type(8))) short short8;   // 8 x bf16 MFMA frag
typedef __attribute__((ext_vector_type(4))) float f32x4;    // MFMA accumulator
typedef __attribute__((ext_vector_type(2))) float f32x2;    // packed pair -> v_pk_fma_f32

static __device__ __forceinline__ float fastrcp(float x) {
    return __builtin_amdgcn_rcpf(x);    // v_rcp_f32, ~1e-7 rel err
}
static __device__ __forceinline__ float fastsqrt(float x) {
    return __builtin_amdgcn_sqrtf(x);   // raw v_sqrt_f32
}
// bf16 pair (packed in unsigned, lo=elem0, hi=elem1) -> two f32 (exact: bf16 is
// truncated f32, so <<16 / mask reconstructs the f32 bit pattern directly)
static __device__ __forceinline__ f32x2 unpk(unsigned u) {
    union { unsigned v; float f; } lo, hi;
    lo.v = u << 16;
    hi.v = u & 0xFFFF0000u;
    return (f32x2){lo.f, hi.f};
}

// LDS bf16 tile, XOR-swizzled: row r, k-elt k at ushort idx
//   r*64 + (((k>>3) ^ (r&7)) << 3) + (k&7)
// 512 threads = 8 waves; wave w owns C rows 16w..16w+15, all 128 cols.
// Lane (lx=l&15, lh=l>>4) owns rows 16w+4lh+q (q<4), cols 16tc+lx (tc<8).
// BOTH K and C stored as packed bf16 pairs (16+16 regs) -> per-thread state 32.
// (bf16 K is exact here: all K = exp(~-226) underflow to 0.0f which bf16
// represents exactly; r1-r7 absmax == 0.0 throughout.)
// bounds(512,6): reg cap 85, 3 blocks/CU. r5's spill at this cap was with
// 48-reg state; 32-reg state + lean phases fits. Tripwire: WRITE_SIZE must
// stay ~64 KB (r5/r7 spills showed up as 73-102 MB there).
__global__ __launch_bounds__(512, 6)
void sinkhorn_batch(const float* __restrict__ srcg,
                    const float* __restrict__ tgtg,
                    float* __restrict__ lossg)
{
    __shared__ ushort sA[N * 64];          // src bf16, swizzled (16 KB)
    __shared__ ushort sB[N * 64];          // tgt bf16, swizzled (16 KB)
    __shared__ float sX2[N], sY2[N], sV[N];
    __shared__ float sPart[8][8][16];      // [wave][colTile][lx] partials (4 KB)
    __shared__ float sRed[8];

    const int t  = threadIdx.x;
    const int l  = t & 63;
    const int w  = t >> 6;       // wave 0..7
    const int lx = l & 15;
    const int lh = l >> 4;       // 0..3
    const int bt = blockIdx.x;

    const float4* sg4 = reinterpret_cast<const float4*>(srcg + (size_t)bt * (N * 64));
    const float4* tg4 = reinterpret_cast<const float4*>(tgtg + (size_t)bt * (N * 64));

    // ---- phase 0: stage bf16 (swizzled) + fp32 row norms, fused butterfly ----
    #pragma unroll
    for (int it = 0; it < 4; ++it) {
        int f  = t + 512 * it;    // 0..2047 float4s; 16 consecutive lanes = one row
        int r  = f >> 4;
        int d4 = f & 15;
        float4 a = sg4[f];
        float4 b = tg4[f];
        float pa = a.x * a.x + a.y * a.y + a.z * a.z + a.w * a.w;
        float pb = b.x * b.x + b.y * b.y + b.z * b.z + b.w * b.w;
        // lanes g<8 carry pa, g>=8 carry pb (one exchange), then 8-lane tree
        float x = (lx & 8) ? pb : pa;
        float y = (lx & 8) ? pa : pb;
        x += __shfl_xor(y, 8);
        x += __shfl_xor(x, 1);
        x += __shfl_xor(x, 2);
        x += __shfl_xor(x, 4);
        if ((lx & 7) == 0) ((lx & 8) ? sY2 : sX2)[r] = x;

        int idx = r * 64 + (((d4 >> 1) ^ (r & 7)) << 3) + (d4 & 1) * 4;
        union { __hip_bfloat162 h[2]; ushort4 u; } ca, cb;
        ca.h[0] = __float22bfloat162_rn(make_float2(a.x, a.y));
        ca.h[1] = __float22bfloat162_rn(make_float2(a.z, a.w));
        cb.h[0] = __float22bfloat162_rn(make_float2(b.x, b.y));
        cb.h[1] = __float22bfloat162_rn(make_float2(b.z, b.w));
        *reinterpret_cast<ushort4*>(&sA[idx]) = ca.u;
        *reinterpret_cast<ushort4*>(&sB[idx]) = cb.u;
    }
    __syncthreads();

    // ---- phase 1+2 fused: per col-tile MFMA -> C,K (acc lives 4 regs at a time) --
    float x2r[4], y2c[8];
    #pragma unroll
    for (int q = 0; q < 4; ++q) x2r[q] = sX2[16 * w + 4 * lh + q];
    #pragma unroll
    for (int tc = 0; tc < 8; ++tc) y2c[tc] = sY2[16 * tc + lx];

    short8 af0, af1;
    {
        int ra = 16 * w + lx;
        af0 = *reinterpret_cast<const short8*>(&sA[ra * 64 + (((0 + lh) ^ (ra & 7)) << 3)]);
        af1 = *reinterpret_cast<const short8*>(&sA[ra * 64 + (((4 + lh) ^ (ra & 7)) << 3)]);
    }

    unsigned kkp[8][2];   // packed bf16 K: (bf16(K[2p+1])<<16)|bf16(K[2p])
    unsigned ccp[8][2];   // packed bf16 C
    #pragma unroll
    for (int tc = 0; tc < 8; ++tc) {
        int rb = 16 * tc + lx;
        short8 bf0 = *reinterpret_cast<const short8*>(&sB[rb * 64 + (((0 + lh) ^ (rb & 7)) << 3)]);
        short8 bf1 = *reinterpret_cast<const short8*>(&sB[rb * 64 + (((4 + lh) ^ (rb & 7)) << 3)]);
        f32x4 acc = (f32x4){0.f, 0.f, 0.f, 0.f};
        acc = __builtin_amdgcn_mfma_f32_16x16x32_bf16(af0, bf0, acc, 0, 0, 0);
        acc = __builtin_amdgcn_mfma_f32_16x16x32_bf16(af1, bf1, acc, 0, 0, 0);
        float cd[4];
        #pragma unroll
        for (int q = 0; q < 4; ++q) {
            float d2 = x2r[q] + y2c[tc] - 2.0f * acc[q];
            cd[q] = fastsqrt(fmaxf(d2, 0.f));
        }
        union { __hip_bfloat162 h; unsigned u; } k0, k1, p0, p1;
        k0.h = __float22bfloat162_rn(make_float2(__expf(-INVTAU * cd[0]), __expf(-INVTAU * cd[1])));
        k1.h = __float22bfloat162_rn(make_float2(__expf(-INVTAU * cd[2]), __expf(-INVTAU * cd[3])));
        kkp[tc][0] = k0.u;
        kkp[tc][1] = k1.u;
        p0.h = __float22bfloat162_rn(make_float2(cd[0], cd[1]));
        p1.h = __float22bfloat162_rn(make_float2(cd[2], cd[3]));
        ccp[tc][0] = p0.u;
        ccp[tc][1] = p1.u;
    }

    if (t < N) sV[t] = 1.0f;
    __syncthreads();

    // ---- phase 3: Sinkhorn; u register-resident, packed FMAs, bf16-unpacked K --
    f32x2 uu2[2];
    for (int iter = 0; iter < 5; ++iter) {
        // u_i = mu / (sum_j K[i][j] v[j] + eps): reduce over cols (lx in-wave)
        float vv[8];
        #pragma unroll
        for (int tc = 0; tc < 8; ++tc) vv[tc] = sV[16 * tc + lx];
        f32x2 p0 = (f32x2){0.f, 0.f}, p1 = (f32x2){0.f, 0.f};
        #pragma unroll
        for (int tc = 0; tc < 8; ++tc) {
            f32x2 vb = (f32x2){vv[tc], vv[tc]};
            p0 = unpk(kkp[tc][0]) * vb + p0;      // v_pk_fma_f32
            p1 = unpk(kkp[tc][1]) * vb + p1;
        }
        float s0 = p0.x, s1 = p0.y, s2 = p1.x, s3 = p1.y;
        s0 += __shfl_xor(s0, 1); s1 += __shfl_xor(s1, 1); s2 += __shfl_xor(s2, 1); s3 += __shfl_xor(s3, 1);
        s0 += __shfl_xor(s0, 2); s1 += __shfl_xor(s1, 2); s2 += __shfl_xor(s2, 2); s3 += __shfl_xor(s3, 2);
        s0 += __shfl_xor(s0, 4); s1 += __shfl_xor(s1, 4); s2 += __shfl_xor(s2, 4); s3 += __shfl_xor(s3, 4);
        s0 += __shfl_xor(s0, 8); s1 += __shfl_xor(s1, 8); s2 += __shfl_xor(s2, 8); s3 += __shfl_xor(s3, 8);
        uu2[0] = (f32x2){MUF * fastrcp(s0 + EPSF), MUF * fastrcp(s1 + EPSF)};
        uu2[1] = (f32x2){MUF * fastrcp(s2 + EPSF), MUF * fastrcp(s3 + EPSF)};
        // no barrier: u never touches LDS

        // v_j = nu / (sum_i K[i][j] u[i] + eps): reduce over rows
        #pragma unroll
        for (int tc = 0; tc < 8; ++tc) {
            f32x2 t2 = unpk(kkp[tc][0]) * uu2[0] + unpk(kkp[tc][1]) * uu2[1];
            float qc = t2.x + t2.y;
            qc += __shfl_xor(qc, 16);
            qc += __shfl_xor(qc, 32);
            if (l < 16) sPart[w][tc][lx] = qc;
        }
        __syncthreads();
        if (t < N) {
            int b = t >> 4, x = t & 15;
            float s = sPart[0][b][x] + sPart[1][b][x] + sPart[2][b][x] + sPart[3][b][x]
                    + sPart[4][b][x] + sPart[5][b][x] + sPart[6][b][x] + sPart[7][b][x];
            sV[t] = MUF * fastrcp(s + EPSF);
        }
        __syncthreads();
    }

    // ---- phase 4: loss = sum u_i K_ij C_ij v_j (u, K, C register-resident) ----
    float vc[8];
    #pragma unroll
    for (int tc = 0; tc < 8; ++tc) vc[tc] = sV[16 * tc + lx];

    float part = 0.f;
    #pragma unroll
    for (int tc = 0; tc < 8; ++tc) {
        f32x2 r2 = uu2[0] * unpk(kkp[tc][0]) * unpk(ccp[tc][0])
                 + uu2[1] * unpk(kkp[tc][1]) * unpk(ccp[tc][1]);
        part += (r2.x + r2.y) * vc[tc];
    }

    // deterministic block reduce
    #pragma unroll
    for (int off = 32; off >= 1; off >>= 1)
        part += __shfl_xor(part, off);
    if (l == 0) sRed[w] = part;
    __syncthreads();
    if (t == 0) {
        float s = 0.f;
        #pragma unroll
        for (int i = 0; i < 8; ++i) s += sRed[i];
        lossg[bt] = s;
    }
}

// mean over 2048 per-frame losses -> d_out[0]
__global__ __launch_bounds__(256, 1)
void reduce_mean(const float* __restrict__ lossg, float* __restrict__ out)
{
    __shared__ float sRed[4];
    int t = threadIdx.x;
    float s = 0.f;
    #pragma unroll
    for (int it = 0; it < 8; ++it) s += lossg[t + 256 * it];
    #pragma unroll
    for (int off = 32; off >= 1; off >>= 1) s += __shfl_xor(s, off);
    if ((t & 63) == 0) sRed[t >> 6] = s;
    __syncthreads();
    if (t == 0) out[0] = (sRed[0] + sRed[1] + sRed[2] + sRed[3]) * (1.0f / 2048.0f);
}

extern "C" void kernel_launch(void* const* d_in, const int* in_sizes, int n_in,
                              void* d_out, int out_size, void* d_ws, size_t ws_size,
                              hipStream_t stream)
{
    const float* src = (const float*)d_in[0];
    const float* tgt = (const float*)d_in[1];
    float* ws = (float*)d_ws;                       // 2048 floats of scratch

    sinkhorn_batch<<<NBATCH, 512, 0, stream>>>(src, tgt, ws);
    reduce_mean<<<1, 256, 0, stream>>>(ws, (float*)d_out);
}

// Round 10
// 44.085 us; speedup vs baseline: 1.8544x; 1.5781x over previous
//
#include <hip/hip_runtime.h>
#include <hip/hip_bf16.h>

constexpr int NBATCH = 2048;   // B*T
constexpr int N      = 128;    // nodes
constexpr float INVTAU = 20.0f;   // 1/0.05
constexpr float EPSF   = 1e-8f;
constexpr float MUF    = 1.0f / 128.0f;   // mu = nu = 1/N

typedef __attribute__((ext_vector_type(8))) short short8;   // 8 x bf16 MFMA frag
typedef __attribute__((ext_vector_type(4))) float f32x4;    // MFMA accumulator
typedef __attribute__((ext_vector_type(2))) float f32x2;    // packed pair -> v_pk_fma_f32

static __device__ __forceinline__ float fastrcp(float x) {
    return __builtin_amdgcn_rcpf(x);    // v_rcp_f32, ~1e-7 rel err
}
static __device__ __forceinline__ float fastsqrt(float x) {
    return __builtin_amdgcn_sqrtf(x);   // raw v_sqrt_f32
}

// DPP add: s + rotate(s) within the 16-lane DPP row — VALU pipe, NO LDS/DS op.
// (r8 post-mortem: __shfl_xor = DS op; the per-CU LDS pipe is the saturated
// resource, so reductions move to DPP.) ctrl must be an immediate -> template.
template <int CTRL>
static __device__ __forceinline__ float dpp_add(float s) {
    union { float f; int i; } a, b;
    a.f = s;
    b.i = __builtin_amdgcn_update_dpp(0, a.i, CTRL, 0xF, 0xF, false);
    return s + b.f;
}
// full all-reduce over the 16-lane row: row_ror 8,4,2,1 (rotation sums all 16)
static __device__ __forceinline__ float row16_allreduce(float s) {
    s = dpp_add<0x128>(s);   // row_ror:8
    s = dpp_add<0x124>(s);   // row_ror:4
    s = dpp_add<0x122>(s);   // row_ror:2
    s = dpp_add<0x121>(s);   // row_ror:1
    return s;
}

// LDS bf16 tile, XOR-swizzled: row r, k-elt k at ushort idx
//   r*64 + (((k>>3) ^ (r&7)) << 3) + (k&7)
// 512 threads = 8 waves; wave w owns C rows 16w..16w+15, all 128 cols.
// Lane (lx=l&15, lh=l>>4) owns rows 16w+4lh+q (q<4), cols 16tc+lx (tc<8).
// kk fp32 f32x2 pairs (packed FMA), C packed bf16. bounds(512,4): no spill
// (r5/r7 tripwire: WRITE_SIZE must stay ~64 KB).
__global__ __launch_bounds__(512, 4)
void sinkhorn_batch(const float* __restrict__ srcg,
                    const float* __restrict__ tgtg,
                    float* __restrict__ lossg)
{
    // staging 32 KB; dead after phase 1 -> overlaid by sPart (128 cols x 36 f32)
    __shared__ ushort sStage[2 * N * 64];
    __shared__ float sX2[N], sY2[N], sV[N];
    __shared__ float sRed[8];

    ushort* sA = sStage;
    ushort* sB = sStage + N * 64;
    float*  sPartF = reinterpret_cast<float*>(sStage);   // [col][36], 18 KB

    const int t  = threadIdx.x;
    const int l  = t & 63;
    const int w  = t >> 6;       // wave 0..7
    const int lx = l & 15;
    const int lh = l >> 4;       // 0..3
    const int bt = blockIdx.x;

    const float4* sg4 = reinterpret_cast<const float4*>(srcg + (size_t)bt * (N * 64));
    const float4* tg4 = reinterpret_cast<const float4*>(tgtg + (size_t)bt * (N * 64));

    // ---- phase 0: stage bf16 (swizzled) + fp32 row norms via DPP (no DS) ----
    #pragma unroll
    for (int it = 0; it < 4; ++it) {
        int f  = t + 512 * it;    // 0..2047 float4s; 16 consecutive lanes = one row
        int r  = f >> 4;
        int d4 = f & 15;
        float4 a = sg4[f];
        float4 b = tg4[f];
        float pa = a.x * a.x + a.y * a.y + a.z * a.z + a.w * a.w;
        float pb = b.x * b.x + b.y * b.y + b.z * b.z + b.w * b.w;
        pa = row16_allreduce(pa);
        pb = row16_allreduce(pb);
        if ((t & 15) == 0) { sX2[r] = pa; sY2[r] = pb; }

        int idx = r * 64 + (((d4 >> 1) ^ (r & 7)) << 3) + (d4 & 1) * 4;
        union { __hip_bfloat162 h[2]; ushort4 u; } ca, cb;
        ca.h[0] = __float22bfloat162_rn(make_float2(a.x, a.y));
        ca.h[1] = __float22bfloat162_rn(make_float2(a.z, a.w));
        cb.h[0] = __float22bfloat162_rn(make_float2(b.x, b.y));
        cb.h[1] = __float22bfloat162_rn(make_float2(b.z, b.w));
        *reinterpret_cast<ushort4*>(&sA[idx]) = ca.u;
        *reinterpret_cast<ushort4*>(&sB[idx]) = cb.u;
    }
    __syncthreads();

    // ---- phase 1+2 fused: per col-tile MFMA -> C,K (acc lives 4 regs at a time) --
    float x2r[4], y2c[8];
    #pragma unroll
    for (int q = 0; q < 4; ++q) x2r[q] = sX2[16 * w + 4 * lh + q];
    #pragma unroll
    for (int tc = 0; tc < 8; ++tc) y2c[tc] = sY2[16 * tc + lx];

    short8 af0, af1;
    {
        int ra = 16 * w + lx;
        af0 = *reinterpret_cast<const short8*>(&sA[ra * 64 + (((0 + lh) ^ (ra & 7)) << 3)]);
        af1 = *reinterpret_cast<const short8*>(&sA[ra * 64 + (((4 + lh) ^ (ra & 7)) << 3)]);
    }

    f32x2 kk2[8][2];      // kk2[tc][p] = {K[q=2p], K[q=2p+1]} (fp32, r6 form)
    unsigned ccp[8][2];   // packed bf16 C
    #pragma unroll
    for (int tc = 0; tc < 8; ++tc) {
        int rb = 16 * tc + lx;
        short8 bf0 = *reinterpret_cast<const short8*>(&sB[rb * 64 + (((0 + lh) ^ (rb & 7)) << 3)]);
        short8 bf1 = *reinterpret_cast<const short8*>(&sB[rb * 64 + (((4 + lh) ^ (rb & 7)) << 3)]);
        f32x4 acc = (f32x4){0.f, 0.f, 0.f, 0.f};
        acc = __builtin_amdgcn_mfma_f32_16x16x32_bf16(af0, bf0, acc, 0, 0, 0);
        acc = __builtin_amdgcn_mfma_f32_16x16x32_bf16(af1, bf1, acc, 0, 0, 0);
        float cd[4];
        #pragma unroll
        for (int q = 0; q < 4; ++q) {
            float d2 = x2r[q] + y2c[tc] - 2.0f * acc[q];
            cd[q] = fastsqrt(fmaxf(d2, 0.f));
        }
        kk2[tc][0] = (f32x2){__expf(-INVTAU * cd[0]), __expf(-INVTAU * cd[1])};
        kk2[tc][1] = (f32x2){__expf(-INVTAU * cd[2]), __expf(-INVTAU * cd[3])};
        union { __hip_bfloat162 h; unsigned u; } p0, p1;
        p0.h = __float22bfloat162_rn(make_float2(cd[0], cd[1]));
        p1.h = __float22bfloat162_rn(make_float2(cd[2], cd[3]));
        ccp[tc][0] = p0.u;
        ccp[tc][1] = p1.u;
    }

    if (t < N) sV[t] = 1.0f;
    __syncthreads();   // staging reads done -> region becomes sPartF

    // ---- phase 3: Sinkhorn; u via DPP all-reduce (no DS), v via padded LDS ----
    f32x2 uu2[2];
    for (int iter = 0; iter < 5; ++iter) {
        // u_i = mu / (sum_j K[i][j] v[j] + eps): packed dots + DPP row-reduce
        float vv[8];
        #pragma unroll
        for (int tc = 0; tc < 8; ++tc) vv[tc] = sV[16 * tc + lx];
        f32x2 p0 = (f32x2){0.f, 0.f}, p1 = (f32x2){0.f, 0.f};
        #pragma unroll
        for (int tc = 0; tc < 8; ++tc) {
            f32x2 vb = (f32x2){vv[tc], vv[tc]};
            p0 = kk2[tc][0] * vb + p0;      // v_pk_fma_f32
            p1 = kk2[tc][1] * vb + p1;
        }
        float s0 = row16_allreduce(p0.x);
        float s1 = row16_allreduce(p0.y);
        float s2 = row16_allreduce(p1.x);
        float s3 = row16_allreduce(p1.y);
        uu2[0] = (f32x2){MUF * fastrcp(s0 + EPSF), MUF * fastrcp(s1 + EPSF)};
        uu2[1] = (f32x2){MUF * fastrcp(s2 + EPSF), MUF * fastrcp(s3 + EPSF)};
        // no barrier: u never touches LDS

        // v_j = nu / (sum_i K[i][j] u[i] + eps): per-lane 4-row partial ->
        // sPartF[col][w*4+lh] (stride 36: 2-way write aliasing = free),
        // then 128 threads cross-reduce with 8x b128 reads.
        #pragma unroll
        for (int tc = 0; tc < 8; ++tc) {
            f32x2 t2 = kk2[tc][0] * uu2[0] + kk2[tc][1] * uu2[1];
            sPartF[(tc * 16 + lx) * 36 + (w << 2) + lh] = t2.x + t2.y;
        }
        __syncthreads();
        if (t < N) {
            const f32x4* pr = reinterpret_cast<const f32x4*>(&sPartF[t * 36]);
            f32x4 a0 = pr[0], a1 = pr[1], a2 = pr[2], a3 = pr[3];
            f32x4 a4 = pr[4], a5 = pr[5], a6 = pr[6], a7 = pr[7];
            f32x4 ss = a0 + a1 + a2 + a3 + a4 + a5 + a6 + a7;
            float s = (ss[0] + ss[1]) + (ss[2] + ss[3]);
            sV[t] = MUF * fastrcp(s + EPSF);
        }
        __syncthreads();
    }

    // ---- phase 4: loss = sum u_i K_ij C_ij v_j (u, K, C register-resident) ----
    float vc[8];
    #pragma unroll
    for (int tc = 0; tc < 8; ++tc) vc[tc] = sV[16 * tc + lx];

    float part = 0.f;
    #pragma unroll
    for (int tc = 0; tc < 8; ++tc) {
        union { unsigned u; float f; } e0, e1, e2, e3;
        e0.u = ccp[tc][0] << 16;
        e1.u = ccp[tc][0] & 0xFFFF0000u;
        e2.u = ccp[tc][1] << 16;
        e3.u = ccp[tc][1] & 0xFFFF0000u;
        f32x2 c0 = (f32x2){e0.f, e1.f};
        f32x2 c1 = (f32x2){e2.f, e3.f};
        f32x2 r2 = uu2[0] * kk2[tc][0] * c0 + uu2[1] * kk2[tc][1] * c1;
        part += (r2.x + r2.y) * vc[tc];
    }

    // deterministic block reduce: DPP within 16, then 2 cross-row shuffles
    part = row16_allreduce(part);
    part += __shfl_xor(part, 16);
    part += __shfl_xor(part, 32);
    if (l == 0) sRed[w] = part;
    __syncthreads();
    if (t == 0) {
        float s = 0.f;
        #pragma unroll
        for (int i = 0; i < 8; ++i) s += sRed[i];
        lossg[bt] = s;
    }
}

// mean over 2048 per-frame losses -> d_out[0]
__global__ __launch_bounds__(256, 1)
void reduce_mean(const float* __restrict__ lossg, float* __restrict__ out)
{
    __shared__ float sRed[4];
    int t = threadIdx.x;
    float s = 0.f;
    #pragma unroll
    for (int it = 0; it < 8; ++it) s += lossg[t + 256 * it];
    #pragma unroll
    for (int off = 32; off >= 1; off >>= 1) s += __shfl_xor(s, off);
    if ((t & 63) == 0) sRed[t >> 6] = s;
    __syncthreads();
    if (t == 0) out[0] = (sRed[0] + sRed[1] + sRed[2] + sRed[3]) * (1.0f / 2048.0f);
}

extern "C" void kernel_launch(void* const* d_in, const int* in_sizes, int n_in,
                              void* d_out, int out_size, void* d_ws, size_t ws_size,
                              hipStream_t stream)
{
    const float* src = (const float*)d_in[0];
    const float* tgt = (const float*)d_in[1];
    float* ws = (float*)d_ws;                       // 2048 floats of scratch

    sinkhorn_batch<<<NBATCH, 512, 0, stream>>>(src, tgt, ws);
    reduce_mean<<<1, 256, 0, stream>>>(ws, (float*)d_out);
}

// Round 11
// 42.904 us; speedup vs baseline: 1.9054x; 1.0275x over previous
//
#include <hip/hip_runtime.h>
#include <hip/hip_bf16.h>

constexpr int NBATCH = 2048;   // B*T
constexpr int N      = 128;    // nodes
constexpr float INVTAU = 20.0f;   // 1/0.05
constexpr float EPSF   = 1e-8f;
constexpr float MUF    = 1.0f / 128.0f;   // mu = nu = 1/N

typedef __attribute__((ext_vector_type(8))) short short8;   // 8 x bf16 MFMA frag
typedef __attribute__((ext_vector_type(4))) float f32x4;    // MFMA accumulator
typedef __attribute__((ext_vector_type(2))) float f32x2;    // packed pair -> v_pk_fma_f32

static __device__ __forceinline__ float fastrcp(float x) {
    return __builtin_amdgcn_rcpf(x);    // v_rcp_f32, ~1e-7 rel err
}
static __device__ __forceinline__ float fastsqrt(float x) {
    return __builtin_amdgcn_sqrtf(x);   // raw v_sqrt_f32
}

// DPP add: VALU-pipe cross-lane, NO DS op (r10: DS pipe is the bottleneck).
template <int CTRL>
static __device__ __forceinline__ float dpp_add(float s) {
    union { float f; int i; } a, b;
    a.f = s;
    b.i = __builtin_amdgcn_update_dpp(0, a.i, CTRL, 0xF, 0xF, false);
    return s + b.f;
}
// all-reduce over a 16-lane row: row_ror 8,4,2,1
static __device__ __forceinline__ float row16_allreduce(float s) {
    s = dpp_add<0x128>(s);   // row_ror:8
    s = dpp_add<0x124>(s);   // row_ror:4
    s = dpp_add<0x122>(s);   // row_ror:2
    s = dpp_add<0x121>(s);   // row_ror:1
    return s;
}
// all-reduce over an 8-lane group: quad_perm xor1, xor2, then half_mirror
static __device__ __forceinline__ float grp8_allreduce(float s) {
    s = dpp_add<0x0B1>(s);   // quad_perm [1,0,3,2]  (xor 1)
    s = dpp_add<0x04E>(s);   // quad_perm [2,3,0,1]  (xor 2)
    s = dpp_add<0x141>(s);   // row_half_mirror      (xor 7 within 8)
    return s;
}

// LDS bf16 tile, XOR-swizzled: row r, k-elt k at ushort idx
//   r*64 + (((k>>3) ^ (r&7)) << 3) + (k&7)
// 512 threads = 8 waves; wave w owns C rows 16w..16w+15, all 128 cols.
// Lane (lx=l&15, lh=l>>4) owns rows 16w+4lh+q (q<4), cols 16tc+lx (tc<8).
// v stored TRANSPOSED: sVt[lx*12 + tc] = v[16tc+lx] -> per-iter vv read is
// 2x ds_read_b128 instead of 8 scalar reads (stride 12 floats = 48 B:
// 16B-aligned, ~2-way banks). kk fp32 f32x2 pairs, C packed bf16.
// bounds(512,4): no spill (tripwire: WRITE_SIZE ~64 KB).
__global__ __launch_bounds__(512, 4)
void sinkhorn_batch(const float* __restrict__ srcg,
                    const float* __restrict__ tgtg,
                    float* __restrict__ lossg)
{
    // staging 32 KB; dead after phase 1 -> overlaid by sPart (128 cols x 36 f32)
    __shared__ ushort sStage[2 * N * 64];
    __shared__ float sX2[N], sY2[N];
    __shared__ float sVt[16 * 12];         // transposed v
    __shared__ float sRed[8];

    ushort* sA = sStage;
    ushort* sB = sStage + N * 64;
    float*  sPartF = reinterpret_cast<float*>(sStage);   // [col][36], 18 KB

    const int t  = threadIdx.x;
    const int l  = t & 63;
    const int w  = t >> 6;       // wave 0..7
    const int lx = l & 15;
    const int lh = l >> 4;       // 0..3
    const int bt = blockIdx.x;

    const float4* sg4 = reinterpret_cast<const float4*>(srcg + (size_t)bt * (N * 64));
    const float4* tg4 = reinterpret_cast<const float4*>(tgtg + (size_t)bt * (N * 64));

    // ---- phase 0: stage bf16 (swizzled, b128 stores) + norms via 8-lane DPP ----
    #pragma unroll
    for (int it = 0; it < 2; ++it) {
        int tp = t + 512 * it;         // 0..1023; 8 consecutive lanes = one row
        int r  = tp >> 3;
        int d8 = tp & 7;
        int f0 = tp * 2;
        float4 a0 = sg4[f0], a1 = sg4[f0 + 1];
        float4 b0 = tg4[f0], b1 = tg4[f0 + 1];
        float pa = a0.x * a0.x + a0.y * a0.y + a0.z * a0.z + a0.w * a0.w
                 + a1.x * a1.x + a1.y * a1.y + a1.z * a1.z + a1.w * a1.w;
        float pb = b0.x * b0.x + b0.y * b0.y + b0.z * b0.z + b0.w * b0.w
                 + b1.x * b1.x + b1.y * b1.y + b1.z * b1.z + b1.w * b1.w;
        pa = grp8_allreduce(pa);
        pb = grp8_allreduce(pb);
        if (d8 == 0) { sX2[r] = pa; sY2[r] = pb; }

        int idx = r * 64 + ((d8 ^ (r & 7)) << 3);   // b128 slot (16B aligned)
        union { __hip_bfloat162 h[4]; uint4 u; } ca, cb;
        ca.h[0] = __float22bfloat162_rn(make_float2(a0.x, a0.y));
        ca.h[1] = __float22bfloat162_rn(make_float2(a0.z, a0.w));
        ca.h[2] = __float22bfloat162_rn(make_float2(a1.x, a1.y));
        ca.h[3] = __float22bfloat162_rn(make_float2(a1.z, a1.w));
        cb.h[0] = __float22bfloat162_rn(make_float2(b0.x, b0.y));
        cb.h[1] = __float22bfloat162_rn(make_float2(b0.z, b0.w));
        cb.h[2] = __float22bfloat162_rn(make_float2(b1.x, b1.y));
        cb.h[3] = __float22bfloat162_rn(make_float2(b1.z, b1.w));
        *reinterpret_cast<uint4*>(&sA[idx]) = ca.u;
        *reinterpret_cast<uint4*>(&sB[idx]) = cb.u;
    }
    __syncthreads();

    // ---- phase 1+2 fused: per col-tile MFMA -> C,K (acc lives 4 regs at a time) --
    float x2r[4], y2c[8];
    #pragma unroll
    for (int q = 0; q < 4; ++q) x2r[q] = sX2[16 * w + 4 * lh + q];
    #pragma unroll
    for (int tc = 0; tc < 8; ++tc) y2c[tc] = sY2[16 * tc + lx];

    short8 af0, af1;
    {
        int ra = 16 * w + lx;
        af0 = *reinterpret_cast<const short8*>(&sA[ra * 64 + (((0 + lh) ^ (ra & 7)) << 3)]);
        af1 = *reinterpret_cast<const short8*>(&sA[ra * 64 + (((4 + lh) ^ (ra & 7)) << 3)]);
    }

    f32x2 kk2[8][2];      // kk2[tc][p] = {K[q=2p], K[q=2p+1]}
    unsigned ccp[8][2];   // packed bf16 C
    #pragma unroll
    for (int tc = 0; tc < 8; ++tc) {
        int rb = 16 * tc + lx;
        short8 bf0 = *reinterpret_cast<const short8*>(&sB[rb * 64 + (((0 + lh) ^ (rb & 7)) << 3)]);
        short8 bf1 = *reinterpret_cast<const short8*>(&sB[rb * 64 + (((4 + lh) ^ (rb & 7)) << 3)]);
        f32x4 acc = (f32x4){0.f, 0.f, 0.f, 0.f};
        acc = __builtin_amdgcn_mfma_f32_16x16x32_bf16(af0, bf0, acc, 0, 0, 0);
        acc = __builtin_amdgcn_mfma_f32_16x16x32_bf16(af1, bf1, acc, 0, 0, 0);
        float cd[4];
        #pragma unroll
        for (int q = 0; q < 4; ++q) {
            float d2 = x2r[q] + y2c[tc] - 2.0f * acc[q];
            cd[q] = fastsqrt(fmaxf(d2, 0.f));
        }
        kk2[tc][0] = (f32x2){__expf(-INVTAU * cd[0]), __expf(-INVTAU * cd[1])};
        kk2[tc][1] = (f32x2){__expf(-INVTAU * cd[2]), __expf(-INVTAU * cd[3])};
        union { __hip_bfloat162 h; unsigned u; } p0, p1;
        p0.h = __float22bfloat162_rn(make_float2(cd[0], cd[1]));
        p1.h = __float22bfloat162_rn(make_float2(cd[2], cd[3]));
        ccp[tc][0] = p0.u;
        ccp[tc][1] = p1.u;
    }

    if (t < N) sVt[(t & 15) * 12 + (t >> 4)] = 1.0f;
    __syncthreads();   // staging reads done -> region becomes sPartF

    // ---- phase 3: Sinkhorn; u via DPP all-reduce, v via padded LDS partials ----
    f32x2 uu2[2];
    for (int iter = 0; iter < 5; ++iter) {
        // u_i = mu / (sum_j K[i][j] v[j] + eps): packed dots + DPP row-reduce
        f32x4 v03, v47;
        {
            const f32x4* pv = reinterpret_cast<const f32x4*>(&sVt[lx * 12]);
            v03 = pv[0];   // vv[0..3]  = v[16*0+lx .. 16*3+lx]
            v47 = pv[1];   // vv[4..7]
        }
        f32x2 p0 = (f32x2){0.f, 0.f}, p1 = (f32x2){0.f, 0.f};
        #pragma unroll
        for (int tc = 0; tc < 8; ++tc) {
            float vs = (tc < 4) ? v03[tc & 3] : v47[tc & 3];
            f32x2 vb = (f32x2){vs, vs};
            p0 = kk2[tc][0] * vb + p0;      // v_pk_fma_f32
            p1 = kk2[tc][1] * vb + p1;
        }
        float s0 = row16_allreduce(p0.x);
        float s1 = row16_allreduce(p0.y);
        float s2 = row16_allreduce(p1.x);
        float s3 = row16_allreduce(p1.y);
        uu2[0] = (f32x2){MUF * fastrcp(s0 + EPSF), MUF * fastrcp(s1 + EPSF)};
        uu2[1] = (f32x2){MUF * fastrcp(s2 + EPSF), MUF * fastrcp(s3 + EPSF)};
        // no barrier: u never touches LDS

        // v_j = nu / (sum_i K[i][j] u[i] + eps): per-lane 4-row partial ->
        // sPartF[col][w*4+lh] (stride 36), then 128 threads cross-reduce (8x b128).
        #pragma unroll
        for (int tc = 0; tc < 8; ++tc) {
            f32x2 t2 = kk2[tc][0] * uu2[0] + kk2[tc][1] * uu2[1];
            sPartF[(tc * 16 + lx) * 36 + (w << 2) + lh] = t2.x + t2.y;
        }
        __syncthreads();
        if (t < N) {
            const f32x4* pr = reinterpret_cast<const f32x4*>(&sPartF[t * 36]);
            f32x4 a0 = pr[0], a1 = pr[1], a2 = pr[2], a3 = pr[3];
            f32x4 a4 = pr[4], a5 = pr[5], a6 = pr[6], a7 = pr[7];
            f32x4 ss = a0 + a1 + a2 + a3 + a4 + a5 + a6 + a7;
            float s = (ss[0] + ss[1]) + (ss[2] + ss[3]);
            sVt[(t & 15) * 12 + (t >> 4)] = MUF * fastrcp(s + EPSF);
        }
        __syncthreads();
    }

    // ---- phase 4: loss = sum u_i K_ij C_ij v_j (u, K, C register-resident) ----
    f32x4 v03, v47;
    {
        const f32x4* pv = reinterpret_cast<const f32x4*>(&sVt[lx * 12]);
        v03 = pv[0];
        v47 = pv[1];
    }

    float part = 0.f;
    #pragma unroll
    for (int tc = 0; tc < 8; ++tc) {
        union { unsigned u; float f; } e0, e1, e2, e3;
        e0.u = ccp[tc][0] << 16;
        e1.u = ccp[tc][0] & 0xFFFF0000u;
        e2.u = ccp[tc][1] << 16;
        e3.u = ccp[tc][1] & 0xFFFF0000u;
        f32x2 c0 = (f32x2){e0.f, e1.f};
        f32x2 c1 = (f32x2){e2.f, e3.f};
        f32x2 r2 = uu2[0] * kk2[tc][0] * c0 + uu2[1] * kk2[tc][1] * c1;
        float vs = (tc < 4) ? v03[tc & 3] : v47[tc & 3];
        part += (r2.x + r2.y) * vs;
    }

    // deterministic block reduce: DPP within 16, then 2 cross-row shuffles
    part = row16_allreduce(part);
    part += __shfl_xor(part, 16);
    part += __shfl_xor(part, 32);
    if (l == 0) sRed[w] = part;
    __syncthreads();
    if (t == 0) {
        float s = 0.f;
        #pragma unroll
        for (int i = 0; i < 8; ++i) s += sRed[i];
        lossg[bt] = s;
    }
}

// mean over 2048 per-frame losses -> d_out[0]
__global__ __launch_bounds__(256, 1)
void reduce_mean(const float* __restrict__ lossg, float* __restrict__ out)
{
    __shared__ float sRed[4];
    int t = threadIdx.x;
    float s = 0.f;
    #pragma unroll
    for (int it = 0; it < 8; ++it) s += lossg[t + 256 * it];
    #pragma unroll
    for (int off = 32; off >= 1; off >>= 1) s += __shfl_xor(s, off);
    if ((t & 63) == 0) sRed[t >> 6] = s;
    __syncthreads();
    if (t == 0) out[0] = (sRed[0] + sRed[1] + sRed[2] + sRed[3]) * (1.0f / 2048.0f);
}

extern "C" void kernel_launch(void* const* d_in, const int* in_sizes, int n_in,
                              void* d_out, int out_size, void* d_ws, size_t ws_size,
                              hipStream_t stream)
{
    const float* src = (const float*)d_in[0];
    const float* tgt = (const float*)d_in[1];
    float* ws = (float*)d_ws;                       // 2048 floats of scratch

    sinkhorn_batch<<<NBATCH, 512, 0, stream>>>(src, tgt, ws);
    reduce_mean<<<1, 256, 0, stream>>>(ws, (float*)d_out);
}